// Round 2
// baseline (985.641 us; speedup 1.0000x reference)
//
#include <hip/hip_runtime.h>
#include <math.h>

#define N_ROWS 8192
#define DIM    256
#define KNN    10
#define NSLICE 8
#define BM     64
#define BN     64
#define KT     16
#define FLT_BIG 3.0e38f

// ---------------------------------------------------------------- init
__global__ void k_init(float* accum) {
    accum[0] = 0.f;   // loss2 numerator
    accum[1] = 0.f;   // mse numerator
}

// ------------------------------------------- patch extract + sqn + mse
__global__ __launch_bounds__(256) void k_extract(const float* __restrict__ pred,
                                                 const float* __restrict__ maps,
                                                 float* __restrict__ predV,
                                                 float* __restrict__ mapsV,
                                                 float* __restrict__ sqn,
                                                 float* __restrict__ accum) {
    int row = blockIdx.x;          // patch index: b*256 + m*16 + n
    int j   = threadIdx.x;         // element within patch: r*16 + c
    int b = row >> 8;
    int m = (row >> 4) & 15;
    int n = row & 15;
    int r = j >> 4;
    int c = j & 15;
    int src = (b << 16) + ((m * 16 + r) << 8) + (n * 16 + c);
    float p = pred[src];
    float q = maps[src];
    float pv = p * 0.01f;
    float mv = q * 0.01f;
    predV[row * DIM + j] = pv;
    mapsV[row * DIM + j] = mv;
    float sq = mv * mv;
    float d  = q - p;
    float ms = d * d;
    // wave (64) reduce
    for (int off = 32; off; off >>= 1) {
        sq += __shfl_down(sq, off);
        ms += __shfl_down(ms, off);
    }
    __shared__ float s_sq[4], s_ms[4];
    int wave = threadIdx.x >> 6;
    if ((threadIdx.x & 63) == 0) { s_sq[wave] = sq; s_ms[wave] = ms; }
    __syncthreads();
    if (threadIdx.x == 0) {
        sqn[row] = s_sq[0] + s_sq[1] + s_sq[2] + s_sq[3];
        atomicAdd(&accum[1], s_ms[0] + s_ms[1] + s_ms[2] + s_ms[3]);
    }
}

// ------------------------------------------------------ kNN (partial)
// grid (128, 8): blockIdx.x -> 64 i-rows, blockIdx.y -> 1024-wide j slice.
// 256 threads as 16x16; thread (tx,ty) owns rows i0+ty*4+{0..3},
// cols j0+tx*4+{0..3} per 64-wide j tile. Per-thread streaming top-10
// per row (registers, static indexing only), then width-16 shfl merge.
__global__ __launch_bounds__(256) void k_knn(const float* __restrict__ mapsV,
                                             const float* __restrict__ sqn,
                                             float* __restrict__ partv,
                                             int* __restrict__ partj) {
    __shared__ float As[KT][BM];   // [kk][i]
    __shared__ float Bs[KT][BN];   // [kk][j]
    const int i0    = blockIdx.x * BM;
    const int jbase = blockIdx.y * (N_ROWS / NSLICE);
    const int tid = threadIdx.x;
    const int tx = tid & 15, ty = tid >> 4;

    float topv[4][KNN];
    int   topj[4][KNN];
    float curmax[4];
#pragma unroll
    for (int r2 = 0; r2 < 4; ++r2) {
        curmax[r2] = FLT_BIG;
#pragma unroll
        for (int q = 0; q < KNN; ++q) { topv[r2][q] = FLT_BIG; topj[r2][q] = 0x7fffffff; }
    }

    const int lr = tid >> 2;        // staging row 0..63
    const int lc = (tid & 3) * 4;   // staging col group

    for (int jt = 0; jt < (N_ROWS / NSLICE); jt += BN) {
        const int j0 = jbase + jt;
        float acc[4][4];
#pragma unroll
        for (int a = 0; a < 4; ++a)
#pragma unroll
            for (int b2 = 0; b2 < 4; ++b2) acc[a][b2] = 0.f;

        for (int k0 = 0; k0 < DIM; k0 += KT) {
            __syncthreads();
            float4 av = *reinterpret_cast<const float4*>(&mapsV[(i0 + lr) * DIM + k0 + lc]);
            float4 bv = *reinterpret_cast<const float4*>(&mapsV[(j0 + lr) * DIM + k0 + lc]);
            As[lc + 0][lr] = av.x; As[lc + 1][lr] = av.y; As[lc + 2][lr] = av.z; As[lc + 3][lr] = av.w;
            Bs[lc + 0][lr] = bv.x; Bs[lc + 1][lr] = bv.y; Bs[lc + 2][lr] = bv.z; Bs[lc + 3][lr] = bv.w;
            __syncthreads();
#pragma unroll
            for (int kk = 0; kk < KT; ++kk) {
                float4 a = *reinterpret_cast<const float4*>(&As[kk][ty * 4]);
                float4 b = *reinterpret_cast<const float4*>(&Bs[kk][tx * 4]);
                acc[0][0] += a.x * b.x; acc[0][1] += a.x * b.y; acc[0][2] += a.x * b.z; acc[0][3] += a.x * b.w;
                acc[1][0] += a.y * b.x; acc[1][1] += a.y * b.y; acc[1][2] += a.y * b.z; acc[1][3] += a.y * b.w;
                acc[2][0] += a.z * b.x; acc[2][1] += a.z * b.y; acc[2][2] += a.z * b.z; acc[2][3] += a.z * b.w;
                acc[3][0] += a.w * b.x; acc[3][1] += a.w * b.y; acc[3][2] += a.w * b.z; acc[3][3] += a.w * b.w;
            }
        }
        // fold 16 candidate distances into per-row top-10.
        // rank value: sqn[j] - 2*dot  (sqn[i] constant per row -> same order as D)
#pragma unroll
        for (int q = 0; q < 4; ++q) {
            int jj = j0 + tx * 4 + q;
            float vb = sqn[jj];
#pragma unroll
            for (int r2 = 0; r2 < 4; ++r2) {
                float v = vb - 2.f * acc[r2][q];
                if (v < curmax[r2]) {   // strict: earlier (lower) j kept on tie
                    bool done = false;
#pragma unroll
                    for (int q2 = 0; q2 < KNN; ++q2) {
                        if (!done && topv[r2][q2] == curmax[r2]) {
                            topv[r2][q2] = v; topj[r2][q2] = jj; done = true;
                        }
                    }
                    float mnew = topv[r2][0];
#pragma unroll
                    for (int q2 = 1; q2 < KNN; ++q2) mnew = fmaxf(mnew, topv[r2][q2]);
                    curmax[r2] = mnew;
                }
            }
        }
    }

    // merge the 16 per-thread lists of each (ty, r2) row via width-16 shfl.
#pragma unroll
    for (int r2 = 0; r2 < 4; ++r2) {
        int used = 0;
        for (int round = 0; round < KNN; ++round) {
            float bv = FLT_BIG; int bj = 0x7fffffff; int bslot = -1;
#pragma unroll
            for (int q2 = 0; q2 < KNN; ++q2) {
                bool ok = !(used & (1 << q2));
                float v = topv[r2][q2]; int jj = topj[r2][q2];
                if (ok && (v < bv || (v == bv && jj < bj))) { bv = v; bj = jj; bslot = q2; }
            }
            float myv = bv; int myj = bj; int myslot = bslot;
            for (int off = 8; off; off >>= 1) {
                float ov = __shfl_xor(bv, off, 16);
                int   oj = __shfl_xor(bj, off, 16);
                if (ov < bv || (ov == bv && oj < bj)) { bv = ov; bj = oj; }
            }
            if (myslot >= 0 && myv == bv && myj == bj) used |= (1 << myslot);
            if (tx == 0) {
                int orow = i0 + ty * 4 + r2;
                partv[orow * (NSLICE * KNN) + blockIdx.y * KNN + round] = bv;
                partj[orow * (NSLICE * KNN) + blockIdx.y * KNN + round] = bj;
            }
        }
    }
}

// ------------------------------------- final merge (80->10) + loss terms
__global__ __launch_bounds__(256) void k_loss(const float* __restrict__ mapsV,
                                              const float* __restrict__ predV,
                                              const float* __restrict__ partv,
                                              const int* __restrict__ partj,
                                              float* __restrict__ accum) {
    const int row = blockIdx.x;
    const int tid = threadIdx.x;
    __shared__ int nbr[KNN];
    __shared__ float wsums[4];

    if (tid == 0) { wsums[0] = 0.f; wsums[1] = 0.f; wsums[2] = 0.f; wsums[3] = 0.f; }

    if (tid < 64) {                       // wave 0 selects top-10 of 80
        float v0 = partv[row * (NSLICE * KNN) + tid];
        int   ja = partj[row * (NSLICE * KNN) + tid];
        float v1 = (tid < 16) ? partv[row * (NSLICE * KNN) + 64 + tid] : FLT_BIG;
        int   jb = (tid < 16) ? partj[row * (NSLICE * KNN) + 64 + tid] : 0x7fffffff;
        int used = 0;
        for (int round = 0; round < KNN; ++round) {
            float bv = FLT_BIG; int bj = 0x7fffffff; int bslot = -1;
            if (!(used & 1) && (v0 < bv || (v0 == bv && ja < bj))) { bv = v0; bj = ja; bslot = 0; }
            if (!(used & 2) && (v1 < bv || (v1 == bv && jb < bj))) { bv = v1; bj = jb; bslot = 1; }
            float myv = bv; int myj = bj; int myslot = bslot;
            for (int off = 32; off; off >>= 1) {
                float ov = __shfl_xor(bv, off);
                int   oj = __shfl_xor(bj, off);
                if (ov < bv || (ov == bv && oj < bj)) { bv = ov; bj = oj; }
            }
            if (myslot >= 0 && myv == bv && myj == bj) used |= (1 << myslot);
            if (tid == 0) nbr[round] = bj;
        }
    }
    __syncthreads();

    const int wave = tid >> 6;
    const int lane = tid & 63;
    float wsum = 0.f;
    for (int nb = wave; nb < KNN; nb += 4) {
        int jj = nbr[nb];
        int ci = lane * 4;
        float4 mi = *reinterpret_cast<const float4*>(&mapsV[row * DIM + ci]);
        float4 mj = *reinterpret_cast<const float4*>(&mapsV[jj  * DIM + ci]);
        float4 pi = *reinterpret_cast<const float4*>(&predV[row * DIM + ci]);
        float4 pj = *reinterpret_cast<const float4*>(&predV[jj  * DIM + ci]);
        float dx = mi.x - mj.x, dy = mi.y - mj.y, dz = mi.z - mj.z, dw = mi.w - mj.w;
        float s2m = dx * dx + dy * dy + dz * dz + dw * dw;
        float s1m = fabsf(dx) + fabsf(dy) + fabsf(dz) + fabsf(dw);
        float ex = pi.x - pj.x, ey = pi.y - pj.y, ez = pi.z - pj.z, ew = pi.w - pj.w;
        float s2p = ex * ex + ey * ey + ez * ez + ew * ew;
        for (int off = 32; off; off >>= 1) {
            s2m += __shfl_down(s2m, off);
            s1m += __shfl_down(s1m, off);
            s2p += __shfl_down(s2p, off);
        }
        if (lane == 0) {
            float d2  = sqrtf(s2m);
            float d1  = s1m + 1e-8f;
            float wgt = expf(-d2 / d1);
            float pd  = sqrtf(fmaxf(s2p, 0.f));
            wsum += pd * wgt;
        }
    }
    __syncthreads();
    if (lane == 0) wsums[wave] = wsum;
    __syncthreads();
    if (tid == 0) atomicAdd(&accum[0], wsums[0] + wsums[1] + wsums[2] + wsums[3]);
}

// ---------------------------------------------------------------- final
__global__ void k_final(const float* __restrict__ accum,
                        const float* __restrict__ lamda,
                        float* __restrict__ out) {
    float mse   = accum[1] / 2097152.0f;                 // 32*256*256
    float loss2 = accum[0] / (8192.0f * 8192.0f);        // N*N
    out[0] = mse + loss2 * lamda[0];
}

extern "C" void kernel_launch(void* const* d_in, const int* in_sizes, int n_in,
                              void* d_out, int out_size, void* d_ws, size_t ws_size,
                              hipStream_t stream) {
    const float* pred  = (const float*)d_in[0];
    const float* maps  = (const float*)d_in[1];
    const float* lamda = (const float*)d_in[3];
    float* out = (float*)d_out;

    float* ws    = (float*)d_ws;
    float* predV = ws;                                   // 8192*256
    float* mapsV = ws + 2097152;                         // 8192*256
    float* sqn   = ws + 4194304;                         // 8192
    float* partv = ws + 4194304 + 8192;                  // 8192*80
    int*   partj = (int*)(ws + 4194304 + 8192 + 655360); // 8192*80
    float* accum = ws + 4194304 + 8192 + 2 * 655360;     // 2

    k_init<<<dim3(1), dim3(1), 0, stream>>>(accum);
    k_extract<<<dim3(N_ROWS), dim3(256), 0, stream>>>(pred, maps, predV, mapsV, sqn, accum);
    k_knn<<<dim3(N_ROWS / BM, NSLICE), dim3(256), 0, stream>>>(mapsV, sqn, partv, partj);
    k_loss<<<dim3(N_ROWS), dim3(256), 0, stream>>>(mapsV, predV, partv, partj, accum);
    k_final<<<dim3(1), dim3(1), 0, stream>>>(accum, lamda, out);
}

// Round 3
// 686.632 us; speedup vs baseline: 1.4355x; 1.4355x over previous
//
#include <hip/hip_runtime.h>
#include <hip/hip_fp16.h>
#include <math.h>

#define N_ROWS 8192
#define DIM    256
#define KNN    10
#define FLT_BIG 3.0e38f

typedef __attribute__((ext_vector_type(8))) short bf16x8;
typedef __attribute__((ext_vector_type(4))) float f32x4;

__device__ inline unsigned short f2bf(float f) {
    unsigned u = __float_as_uint(f);
    unsigned r = (u + 0x7fff + ((u >> 16) & 1)) >> 16;
    return (unsigned short)r;
}
__device__ inline float bf2f(unsigned short b) {
    return __uint_as_float(((unsigned)b) << 16);
}

// ---------------------------------------------------------------- init
__global__ void k_init(float* accum) {
    accum[0] = 0.f;   // loss2 numerator
    accum[1] = 0.f;   // mse numerator
}

// --------------------------- patch extract -> bf16 + sqn(bf16) + mse
__global__ __launch_bounds__(256) void k_extract(const float* __restrict__ pred,
                                                 const float* __restrict__ maps,
                                                 unsigned short* __restrict__ mapsB,
                                                 float* __restrict__ sqn,
                                                 float* __restrict__ accum) {
    int row = blockIdx.x;          // patch index: b*256 + m*16 + n
    int j   = threadIdx.x;         // element within patch: r*16 + c
    int b = row >> 8, m = (row >> 4) & 15, n = row & 15;
    int r = j >> 4, c = j & 15;
    int src = (b << 16) + ((m * 16 + r) << 8) + (n * 16 + c);
    float p = pred[src];
    float q = maps[src];
    unsigned short mb = f2bf(q * 0.01f);
    mapsB[row * DIM + j] = mb;
    float mv = bf2f(mb);
    float sq = mv * mv;
    float d  = q - p;
    float ms = d * d;
    for (int off = 32; off; off >>= 1) {
        sq += __shfl_down(sq, off);
        ms += __shfl_down(ms, off);
    }
    __shared__ float s_sq[4], s_ms[4];
    int wave = threadIdx.x >> 6;
    if ((threadIdx.x & 63) == 0) { s_sq[wave] = sq; s_ms[wave] = ms; }
    __syncthreads();
    if (threadIdx.x == 0) {
        sqn[row] = s_sq[0] + s_sq[1] + s_sq[2] + s_sq[3];
        atomicAdd(&accum[1], s_ms[0] + s_ms[1] + s_ms[2] + s_ms[3]);
    }
}

// ------------------------------------------- MFMA Gram -> fp16 D-slice
// D[i][jl] = sqn[jbase+jl] - 2 * dot(maps_i, maps_{jbase+jl})  (fp16)
// 128x128 tile, BK=64, 4 waves (2x2), mfma_f32_16x16x32_bf16.
// LDS XOR-swizzle (T2): 16B block c8 -> c8 ^ (row&7) on both write and read.
__global__ __launch_bounds__(256) void k_gram(const unsigned short* __restrict__ mapsB,
                                              const float* __restrict__ sqn,
                                              __half* __restrict__ Ds,
                                              int jbase, int SW) {
    __shared__ unsigned short As[128 * 64];
    __shared__ unsigned short Bs[128 * 64];
    const int tid = threadIdx.x;
    const int i0    = blockIdx.x * 128;
    const int j0loc = blockIdx.y * 128;
    const int jg0   = jbase + j0loc;
    const int l  = tid & 63;
    const int w  = tid >> 6;
    const int wr = w >> 1, wc = w & 1;
    const int sr = tid >> 3;       // 0..31
    const int c8 = tid & 7;        // 16B block within 128B row

    f32x4 acc[4][4];
#pragma unroll
    for (int mm = 0; mm < 4; ++mm)
#pragma unroll
        for (int nn = 0; nn < 4; ++nn)
#pragma unroll
            for (int q = 0; q < 4; ++q) acc[mm][nn][q] = 0.f;

    uint4 ra[4], rb[4];
    auto stage_load = [&](int kt) {
        int k0 = kt * 64;
#pragma unroll
        for (int q = 0; q < 4; ++q) {
            int r = q * 32 + sr;
            ra[q] = *reinterpret_cast<const uint4*>(&mapsB[(i0 + r) * DIM + k0 + c8 * 8]);
            rb[q] = *reinterpret_cast<const uint4*>(&mapsB[(jg0 + r) * DIM + k0 + c8 * 8]);
        }
    };

    stage_load(0);
#pragma unroll
    for (int kt = 0; kt < 4; ++kt) {
        __syncthreads();
#pragma unroll
        for (int q = 0; q < 4; ++q) {
            int r = q * 32 + sr;
            int off = r * 64 + ((c8 ^ (r & 7)) << 3);
            *reinterpret_cast<uint4*>(&As[off]) = ra[q];
            *reinterpret_cast<uint4*>(&Bs[off]) = rb[q];
        }
        __syncthreads();
        if (kt < 3) stage_load(kt + 1);
#pragma unroll
        for (int g = 0; g < 2; ++g) {
            bf16x8 af[4], bfr[4];
            int kb = g * 4 + (l >> 4);
#pragma unroll
            for (int mm = 0; mm < 4; ++mm) {
                int rr = wr * 64 + mm * 16 + (l & 15);
                af[mm] = *reinterpret_cast<const bf16x8*>(&As[rr * 64 + ((kb ^ (rr & 7)) << 3)]);
            }
#pragma unroll
            for (int nn = 0; nn < 4; ++nn) {
                int rr = wc * 64 + nn * 16 + (l & 15);
                bfr[nn] = *reinterpret_cast<const bf16x8*>(&Bs[rr * 64 + ((kb ^ (rr & 7)) << 3)]);
            }
#pragma unroll
            for (int mm = 0; mm < 4; ++mm)
#pragma unroll
                for (int nn = 0; nn < 4; ++nn)
                    acc[mm][nn] = __builtin_amdgcn_mfma_f32_16x16x32_bf16(af[mm], bfr[nn], acc[mm][nn], 0, 0, 0);
        }
    }

    // epilogue: v = sqn[j] - 2*dot -> fp16
    float sj[4];
#pragma unroll
    for (int nn = 0; nn < 4; ++nn)
        sj[nn] = sqn[jg0 + wc * 64 + nn * 16 + (l & 15)];
#pragma unroll
    for (int mm = 0; mm < 4; ++mm) {
#pragma unroll
        for (int nn = 0; nn < 4; ++nn) {
            int ocol = j0loc + wc * 64 + nn * 16 + (l & 15);
#pragma unroll
            for (int q = 0; q < 4; ++q) {
                int orow = i0 + wr * 64 + mm * 16 + (l >> 4) * 4 + q;
                Ds[orow * SW + ocol] = __float2half(sj[nn] - 2.f * acc[mm][nn][q]);
            }
        }
    }
}

// ------------------------------------------ per-(row,slice) top-10
// one wave per row; lane-strided half2 stream -> per-lane top-10 -> merge
__global__ __launch_bounds__(256) void k_topk(const __half* __restrict__ Ds,
                                              int jbase, int SW, int sIdx, int nsk,
                                              __half* __restrict__ partv,
                                              unsigned short* __restrict__ partj) {
    const int row = blockIdx.x * 4 + (threadIdx.x >> 6);
    const int l = threadIdx.x & 63;
    const __half* base = Ds + (size_t)row * SW;

    float tv[KNN]; int tj[KNN];
    float cm = FLT_BIG;
#pragma unroll
    for (int q = 0; q < KNN; ++q) { tv[q] = FLT_BIG; tj[q] = 0x7fffffff; }

    auto insert = [&](float v, int j) {
        if (v < cm) {
            bool done = false;
#pragma unroll
            for (int q = 0; q < KNN; ++q)
                if (!done && tv[q] == cm) { tv[q] = v; tj[q] = j; done = true; }
            float m2 = tv[0];
#pragma unroll
            for (int q = 1; q < KNN; ++q) m2 = fmaxf(m2, tv[q]);
            cm = m2;
        }
    };

    const int nr = SW / 128;
    for (int r = 0; r < nr; ++r) {
        __half2 h2 = *reinterpret_cast<const __half2*>(base + r * 128 + l * 2);
        int j0 = r * 128 + l * 2;
        insert(__low2float(h2), j0);
        insert(__high2float(h2), j0 + 1);
    }

    unsigned used = 0;
    for (int round = 0; round < KNN; ++round) {
        float bv = FLT_BIG; int bj = 0x7fffffff; int bs = -1;
#pragma unroll
        for (int q = 0; q < KNN; ++q) {
            bool ok = !((used >> q) & 1);
            if (ok && (tv[q] < bv || (tv[q] == bv && tj[q] < bj))) { bv = tv[q]; bj = tj[q]; bs = q; }
        }
        float mv = bv; int mj = bj;
        for (int off = 32; off; off >>= 1) {
            float ov = __shfl_xor(bv, off);
            int   oj = __shfl_xor(bj, off);
            if (ov < bv || (ov == bv && oj < bj)) { bv = ov; bj = oj; }
        }
        if (bs >= 0 && mv == bv && mj == bj) used |= (1u << bs);
        if (l == 0) {
            partv[row * nsk + sIdx * KNN + round] = __float2half(bv);
            partj[row * nsk + sIdx * KNN + round] = (unsigned short)(jbase + bj);
        }
    }
}

// -------------------- merge NS*10 partials -> 10 nbrs, loss terms
__global__ __launch_bounds__(256) void k_loss(const float* __restrict__ pred,
                                              const float* __restrict__ maps,
                                              const __half* __restrict__ partv,
                                              const unsigned short* __restrict__ partj,
                                              int nsk,
                                              float* __restrict__ accum) {
    const int row = blockIdx.x;
    const int tid = threadIdx.x;
    __shared__ int nbr[KNN];
    __shared__ float wsums[4];
    if (tid == 0) { wsums[0] = 0.f; wsums[1] = 0.f; wsums[2] = 0.f; wsums[3] = 0.f; }

    if (tid < 64) {
        float v[3]; int jx[3];
#pragma unroll
        for (int u = 0; u < 3; ++u) {
            int e = tid + 64 * u;
            if (e < nsk) {
                v[u]  = __half2float(partv[row * nsk + e]);
                jx[u] = (int)partj[row * nsk + e];
            } else { v[u] = FLT_BIG; jx[u] = 0x7fffffff; }
        }
        unsigned used = 0;
        for (int round = 0; round < KNN; ++round) {
            float bv = FLT_BIG; int bj = 0x7fffffff; int bs = -1;
#pragma unroll
            for (int u = 0; u < 3; ++u) {
                bool ok = !((used >> u) & 1);
                if (ok && (v[u] < bv || (v[u] == bv && jx[u] < bj))) { bv = v[u]; bj = jx[u]; bs = u; }
            }
            float mv = bv; int mj = bj;
            for (int off = 32; off; off >>= 1) {
                float ov = __shfl_xor(bv, off);
                int   oj = __shfl_xor(bj, off);
                if (ov < bv || (ov == bv && oj < bj)) { bv = ov; bj = oj; }
            }
            if (bs >= 0 && mv == bv && mj == bj) used |= (1u << bs);
            if (tid == 0) nbr[round] = bj;
        }
    }
    __syncthreads();

    const int wv = tid >> 6;
    const int l  = tid & 63;
    const int b = row >> 8, m = (row >> 4) & 15, n = row & 15;
    const int r = l >> 2, cb = (l & 3) * 4;
    const int mybase = (b << 16) + ((m * 16 + r) << 8) + (n * 16 + cb);
    const float4 mi = *reinterpret_cast<const float4*>(&maps[mybase]);
    const float4 pi = *reinterpret_cast<const float4*>(&pred[mybase]);

    float wsum = 0.f;
    for (int nb = wv; nb < KNN; nb += 4) {
        int jj = nbr[nb];
        int bj2 = jj >> 8, mj = (jj >> 4) & 15, nj = jj & 15;
        int nbase = (bj2 << 16) + ((mj * 16 + r) << 8) + (nj * 16 + cb);
        float4 mjv = *reinterpret_cast<const float4*>(&maps[nbase]);
        float4 pjv = *reinterpret_cast<const float4*>(&pred[nbase]);
        float dx = (mi.x - mjv.x) * 0.01f, dy = (mi.y - mjv.y) * 0.01f;
        float dz = (mi.z - mjv.z) * 0.01f, dw = (mi.w - mjv.w) * 0.01f;
        float s2m = dx * dx + dy * dy + dz * dz + dw * dw;
        float s1m = fabsf(dx) + fabsf(dy) + fabsf(dz) + fabsf(dw);
        float ex = (pi.x - pjv.x) * 0.01f, ey = (pi.y - pjv.y) * 0.01f;
        float ez = (pi.z - pjv.z) * 0.01f, ew = (pi.w - pjv.w) * 0.01f;
        float s2p = ex * ex + ey * ey + ez * ez + ew * ew;
        for (int off = 32; off; off >>= 1) {
            s2m += __shfl_down(s2m, off);
            s1m += __shfl_down(s1m, off);
            s2p += __shfl_down(s2p, off);
        }
        if (l == 0) {
            float d2  = sqrtf(s2m);
            float d1  = s1m + 1e-8f;
            float wgt = expf(-d2 / d1);
            float pd  = sqrtf(fmaxf(s2p, 0.f));
            wsum += pd * wgt;
        }
    }
    __syncthreads();
    if (l == 0) wsums[wv] = wsum;
    __syncthreads();
    if (tid == 0) atomicAdd(&accum[0], wsums[0] + wsums[1] + wsums[2] + wsums[3]);
}

// ---------------------------------------------------------------- final
__global__ void k_final(const float* __restrict__ accum,
                        const float* __restrict__ lamda,
                        float* __restrict__ out) {
    float mse   = accum[1] / 2097152.0f;                 // 32*256*256
    float loss2 = accum[0] / (8192.0f * 8192.0f);        // N*N
    out[0] = mse + loss2 * lamda[0];
}

extern "C" void kernel_launch(void* const* d_in, const int* in_sizes, int n_in,
                              void* d_out, int out_size, void* d_ws, size_t ws_size,
                              hipStream_t stream) {
    const float* pred  = (const float*)d_in[0];
    const float* maps  = (const float*)d_in[1];
    const float* lamda = (const float*)d_in[3];
    float* out = (float*)d_out;

    // tiered slice width based on workspace size
    int SW, NS;
    if (ws_size >= (41ull << 20))      { SW = 2048; NS = 4;  }
    else if (ws_size >= (26ull << 20)) { SW = 1024; NS = 8;  }
    else                               { SW = 512;  NS = 16; }
    const int nsk = NS * KNN;

    char* W = (char*)d_ws;
    unsigned short* mapsB = (unsigned short*)W;                  // 4 MB
    float* sqn   = (float*)(W + 4194304);                        // 32 KB
    float* accum = (float*)(W + 4194304 + 32768);                // pad to 256 B
    __half* Ds   = (__half*)(W + 4227328);                       // 8192*SW*2 B
    size_t dsB   = (size_t)N_ROWS * SW * 2;
    __half* partv = (__half*)(W + 4227328 + dsB);                // 8192*nsk*2
    unsigned short* partj = (unsigned short*)(W + 4227328 + dsB + (size_t)N_ROWS * nsk * 2);

    k_init<<<dim3(1), dim3(1), 0, stream>>>(accum);
    k_extract<<<dim3(N_ROWS), dim3(256), 0, stream>>>(pred, maps, mapsB, sqn, accum);
    for (int s = 0; s < NS; ++s) {
        k_gram<<<dim3(N_ROWS / 128, SW / 128), dim3(256), 0, stream>>>(mapsB, sqn, Ds, s * SW, SW);
        k_topk<<<dim3(N_ROWS / 4), dim3(256), 0, stream>>>(Ds, s * SW, SW, s, nsk, partv, partj);
    }
    k_loss<<<dim3(N_ROWS), dim3(256), 0, stream>>>(pred, maps, partv, partj, nsk, accum);
    k_final<<<dim3(1), dim3(1), 0, stream>>>(accum, lamda, out);
}

// Round 4
// 404.458 us; speedup vs baseline: 2.4369x; 1.6977x over previous
//
#include <hip/hip_runtime.h>
#include <hip/hip_fp16.h>
#include <math.h>

#define N_ROWS 8192
#define DIM    256
#define KNN    10
#define NS     8
#define SLW    1024
#define FLT_BIG 3.0e38f

typedef __attribute__((ext_vector_type(8))) short bf16x8;
typedef __attribute__((ext_vector_type(4))) float f32x4;

__device__ inline unsigned short f2bf(float f) {
    unsigned u = __float_as_uint(f);
    unsigned r = (u + 0x7fff + ((u >> 16) & 1)) >> 16;
    return (unsigned short)r;
}
__device__ inline float bf2f(unsigned short b) {
    return __uint_as_float(((unsigned)b) << 16);
}

// --------------------------- patch extract -> bf16 + sqn(bf16) + mse part
__global__ __launch_bounds__(256) void k_extract(const float* __restrict__ pred,
                                                 const float* __restrict__ maps,
                                                 unsigned short* __restrict__ mapsB,
                                                 float* __restrict__ sqn,
                                                 float* __restrict__ msePart) {
    int row = blockIdx.x;          // patch index: b*256 + m*16 + n
    int j   = threadIdx.x;         // element within patch: r*16 + c
    int b = row >> 8, m = (row >> 4) & 15, n = row & 15;
    int r = j >> 4, c = j & 15;
    int src = (b << 16) + ((m * 16 + r) << 8) + (n * 16 + c);
    float p = pred[src];
    float q = maps[src];
    unsigned short mb = f2bf(q * 0.01f);
    mapsB[row * DIM + j] = mb;
    float mv = bf2f(mb);
    float sq = mv * mv;
    float d  = q - p;
    float ms = d * d;
    for (int off = 32; off; off >>= 1) {
        sq += __shfl_down(sq, off);
        ms += __shfl_down(ms, off);
    }
    __shared__ float s_sq[4], s_ms[4];
    int wave = threadIdx.x >> 6;
    if ((threadIdx.x & 63) == 0) { s_sq[wave] = sq; s_ms[wave] = ms; }
    __syncthreads();
    if (threadIdx.x == 0) {
        sqn[row] = s_sq[0] + s_sq[1] + s_sq[2] + s_sq[3];
        msePart[row] = s_ms[0] + s_ms[1] + s_ms[2] + s_ms[3];
    }
}

// ------------------- fused MFMA Gram + in-LDS fold -> per-slice top-10
// grid (64, NS). Block: 128 i-rows x SLW j-cols (8 tiles of 128).
// LDS: As/Bs (2x16KB) aliased with fp16 D-tile (32KB).
__global__ __launch_bounds__(256) void k_knn(const unsigned short* __restrict__ mapsB,
                                             const float* __restrict__ sqn,
                                             __half* __restrict__ partv,
                                             unsigned short* __restrict__ partj) {
    __shared__ unsigned short smem[128 * 128];       // 32 KB
    unsigned short* As = smem;                       // [128][64] shorts
    unsigned short* Bs = smem + 128 * 64;
    __half* Dt = (__half*)smem;                      // [128][128] fp16 (aliased)

    const int tid = threadIdx.x;
    const int i0    = blockIdx.x * 128;
    const int slice = blockIdx.y;
    const int l  = tid & 63;
    const int w  = tid >> 6;
    const int wr = w >> 1, wc = w & 1;
    const int sr = tid >> 3;       // staging row 0..31 (+q*32)
    const int c8 = tid & 7;        // 16B block within 128B row
    const int frow = tid >> 1;     // fold row 0..127
    const int fh   = tid & 1;      // fold half (64 cols)

    float tv[KNN]; int tj[KNN];
    float cm = FLT_BIG;
#pragma unroll
    for (int q = 0; q < KNN; ++q) { tv[q] = FLT_BIG; tj[q] = 0x7fffffff; }

    auto insert = [&](float v, int j) {
        if (v < cm) {
            bool done = false;
#pragma unroll
            for (int q = 0; q < KNN; ++q)
                if (!done && tv[q] == cm) { tv[q] = v; tj[q] = j; done = true; }
            float m2 = tv[0];
#pragma unroll
            for (int q = 1; q < KNN; ++q) m2 = fmaxf(m2, tv[q]);
            cm = m2;
        }
    };

    for (int tt = 0; tt < SLW / 128; ++tt) {
        const int jg0 = slice * SLW + tt * 128;

        f32x4 acc[4][4];
#pragma unroll
        for (int mm = 0; mm < 4; ++mm)
#pragma unroll
            for (int nn = 0; nn < 4; ++nn)
#pragma unroll
                for (int q = 0; q < 4; ++q) acc[mm][nn][q] = 0.f;

        uint4 ra[4], rb[4];
        auto stage_load = [&](int kt) {
            int k0 = kt * 64;
#pragma unroll
            for (int q = 0; q < 4; ++q) {
                int r = q * 32 + sr;
                ra[q] = *reinterpret_cast<const uint4*>(&mapsB[(i0 + r) * DIM + k0 + c8 * 8]);
                rb[q] = *reinterpret_cast<const uint4*>(&mapsB[(jg0 + r) * DIM + k0 + c8 * 8]);
            }
        };

        stage_load(0);
#pragma unroll
        for (int kt = 0; kt < 4; ++kt) {
            __syncthreads();   // prev fold / prev kt MFMA reads complete
#pragma unroll
            for (int q = 0; q < 4; ++q) {
                int r = q * 32 + sr;
                int off = r * 64 + ((c8 ^ (r & 7)) << 3);
                *reinterpret_cast<uint4*>(&As[off]) = ra[q];
                *reinterpret_cast<uint4*>(&Bs[off]) = rb[q];
            }
            __syncthreads();
            if (kt < 3) stage_load(kt + 1);
#pragma unroll
            for (int g = 0; g < 2; ++g) {
                bf16x8 af[4], bfr[4];
                int kb = g * 4 + (l >> 4);
#pragma unroll
                for (int mm = 0; mm < 4; ++mm) {
                    int rr = wr * 64 + mm * 16 + (l & 15);
                    af[mm] = *reinterpret_cast<const bf16x8*>(&As[rr * 64 + ((kb ^ (rr & 7)) << 3)]);
                }
#pragma unroll
                for (int nn = 0; nn < 4; ++nn) {
                    int rr = wc * 64 + nn * 16 + (l & 15);
                    bfr[nn] = *reinterpret_cast<const bf16x8*>(&Bs[rr * 64 + ((kb ^ (rr & 7)) << 3)]);
                }
#pragma unroll
                for (int mm = 0; mm < 4; ++mm)
#pragma unroll
                    for (int nn = 0; nn < 4; ++nn)
                        acc[mm][nn] = __builtin_amdgcn_mfma_f32_16x16x32_bf16(af[mm], bfr[nn], acc[mm][nn], 0, 0, 0);
            }
        }

        __syncthreads();       // all MFMA LDS reads done; safe to overwrite with Dt
        float sj[4];
#pragma unroll
        for (int nn = 0; nn < 4; ++nn)
            sj[nn] = sqn[jg0 + wc * 64 + nn * 16 + (l & 15)];
#pragma unroll
        for (int mm = 0; mm < 4; ++mm)
#pragma unroll
            for (int nn = 0; nn < 4; ++nn) {
                int col = wc * 64 + nn * 16 + (l & 15);
#pragma unroll
                for (int q = 0; q < 4; ++q) {
                    int row = wr * 64 + mm * 16 + (l >> 4) * 4 + q;
                    Dt[row * 128 + col] = __float2half(sj[nn] - 2.f * acc[mm][nn][q]);
                }
            }
        __syncthreads();

        // fold: 2 threads per row, row-rotated scan (2-way bank aliasing only)
        const __half2* Drow = reinterpret_cast<const __half2*>(Dt + frow * 128 + fh * 64);
        for (int s = 0; s < 32; ++s) {
            int e = (s + frow) & 31;
            __half2 v2 = Drow[e];
            int jj = jg0 + fh * 64 + e * 2;
            insert(__low2float(v2), jj);
            insert(__high2float(v2), jj + 1);
        }
        // next iteration's first __syncthreads() fences fold-reads vs As/Bs writes
    }

    // merge the two threads of each row (lanes 2k, 2k+1)
    unsigned used = 0;
    for (int round = 0; round < KNN; ++round) {
        float bv = FLT_BIG; int bj = 0x7fffffff; int bs = -1;
#pragma unroll
        for (int q = 0; q < KNN; ++q) {
            bool ok = !((used >> q) & 1);
            if (ok && (tv[q] < bv || (tv[q] == bv && tj[q] < bj))) { bv = tv[q]; bj = tj[q]; bs = q; }
        }
        float mv = bv; int mj = bj;
        float ov = __shfl_xor(bv, 1);
        int   oj = __shfl_xor(bj, 1);
        if (ov < bv || (ov == bv && oj < bj)) { bv = ov; bj = oj; }
        if (bs >= 0 && mv == bv && mj == bj) used |= (1u << bs);
        if (fh == 0) {
            int orow = i0 + frow;
            partv[orow * (NS * KNN) + slice * KNN + round] = __float2half(bv);
            partj[orow * (NS * KNN) + slice * KNN + round] = (unsigned short)bj;
        }
    }
}

// -------------------- merge NS*10 partials -> nbr[8192][10]
__global__ __launch_bounds__(256) void k_merge(const __half* __restrict__ partv,
                                               const unsigned short* __restrict__ partj,
                                               unsigned short* __restrict__ nbr) {
    const int row = blockIdx.x * 4 + (threadIdx.x >> 6);
    const int l = threadIdx.x & 63;
    float v0 = __half2float(partv[row * (NS * KNN) + l]);
    int   j0 = (int)partj[row * (NS * KNN) + l];
    float v1 = (l < 16) ? __half2float(partv[row * (NS * KNN) + 64 + l]) : FLT_BIG;
    int   j1 = (l < 16) ? (int)partj[row * (NS * KNN) + 64 + l] : 0x7fffffff;
    unsigned used = 0;
    for (int round = 0; round < KNN; ++round) {
        float bv = FLT_BIG; int bj = 0x7fffffff; int bs = -1;
        if (!(used & 1) && (v0 < bv || (v0 == bv && j0 < bj))) { bv = v0; bj = j0; bs = 0; }
        if (!(used & 2) && (v1 < bv || (v1 == bv && j1 < bj))) { bv = v1; bj = j1; bs = 1; }
        float mv = bv; int mj = bj;
        for (int off = 32; off; off >>= 1) {
            float ov = __shfl_xor(bv, off);
            int   oj = __shfl_xor(bj, off);
            if (ov < bv || (ov == bv && oj < bj)) { bv = ov; bj = oj; }
        }
        if (bs >= 0 && mv == bv && mj == bj) used |= (1u << bs);
        if (l == 0) nbr[row * KNN + round] = (unsigned short)bj;
    }
}

// -------------------- one wave per (row, nbr) pair -> block partial
__global__ __launch_bounds__(256) void k_pairs(const float* __restrict__ pred,
                                               const float* __restrict__ maps,
                                               const unsigned short* __restrict__ nbr,
                                               float* __restrict__ blockPart) {
    const int p = blockIdx.x * 4 + (threadIdx.x >> 6);   // pair 0..81919
    const int l = threadIdx.x & 63;
    const int row = p / KNN;
    const int jj  = (int)nbr[p];

    const int r = l >> 2, cb = (l & 3) * 4;
    const int bi = row >> 8, mi = (row >> 4) & 15, ni = row & 15;
    const int bj = jj  >> 8, mj = (jj  >> 4) & 15, nj = jj  & 15;
    const int ibase = (bi << 16) + ((mi * 16 + r) << 8) + (ni * 16 + cb);
    const int jbase = (bj << 16) + ((mj * 16 + r) << 8) + (nj * 16 + cb);

    const float4 miv = *reinterpret_cast<const float4*>(&maps[ibase]);
    const float4 piv = *reinterpret_cast<const float4*>(&pred[ibase]);
    const float4 mjv = *reinterpret_cast<const float4*>(&maps[jbase]);
    const float4 pjv = *reinterpret_cast<const float4*>(&pred[jbase]);

    float dx = (miv.x - mjv.x) * 0.01f, dy = (miv.y - mjv.y) * 0.01f;
    float dz = (miv.z - mjv.z) * 0.01f, dw = (miv.w - mjv.w) * 0.01f;
    float s2m = dx * dx + dy * dy + dz * dz + dw * dw;
    float s1m = fabsf(dx) + fabsf(dy) + fabsf(dz) + fabsf(dw);
    float ex = (piv.x - pjv.x) * 0.01f, ey = (piv.y - pjv.y) * 0.01f;
    float ez = (piv.z - pjv.z) * 0.01f, ew = (piv.w - pjv.w) * 0.01f;
    float s2p = ex * ex + ey * ey + ez * ez + ew * ew;
    for (int off = 32; off; off >>= 1) {
        s2m += __shfl_down(s2m, off);
        s1m += __shfl_down(s1m, off);
        s2p += __shfl_down(s2p, off);
    }
    __shared__ float wp[4];
    if (l == 0) {
        float d2  = sqrtf(s2m);
        float d1  = s1m + 1e-8f;
        float wgt = expf(-d2 / d1);
        float pd  = sqrtf(fmaxf(s2p, 0.f));
        wp[threadIdx.x >> 6] = pd * wgt;
    }
    __syncthreads();
    if (threadIdx.x == 0)
        blockPart[blockIdx.x] = wp[0] + wp[1] + wp[2] + wp[3];
}

// ---------------------------------------------------------------- final
__global__ __launch_bounds__(256) void k_final(const float* __restrict__ msePart,
                                               const float* __restrict__ blockPart,
                                               const float* __restrict__ lamda,
                                               float* __restrict__ out) {
    const int tid = threadIdx.x;
    float sm = 0.f, sp = 0.f;
    for (int i = tid; i < N_ROWS; i += 256) sm += msePart[i];
    for (int i = tid; i < (N_ROWS * KNN / 4); i += 256) sp += blockPart[i];
    for (int off = 32; off; off >>= 1) {
        sm += __shfl_down(sm, off);
        sp += __shfl_down(sp, off);
    }
    __shared__ float s_m[4], s_p[4];
    int wave = tid >> 6;
    if ((tid & 63) == 0) { s_m[wave] = sm; s_p[wave] = sp; }
    __syncthreads();
    if (tid == 0) {
        float mse   = (s_m[0] + s_m[1] + s_m[2] + s_m[3]) / 2097152.0f;
        float loss2 = (s_p[0] + s_p[1] + s_p[2] + s_p[3]) / (8192.0f * 8192.0f);
        out[0] = mse + loss2 * lamda[0];
    }
}

extern "C" void kernel_launch(void* const* d_in, const int* in_sizes, int n_in,
                              void* d_out, int out_size, void* d_ws, size_t ws_size,
                              hipStream_t stream) {
    const float* pred  = (const float*)d_in[0];
    const float* maps  = (const float*)d_in[1];
    const float* lamda = (const float*)d_in[3];
    float* out = (float*)d_out;

    char* W = (char*)d_ws;
    unsigned short* mapsB = (unsigned short*)W;                         // 4 MB
    float* sqn     = (float*)(W + 4194304);                             // 32 KB
    float* msePart = (float*)(W + 4194304 + 32768);                     // 32 KB
    __half* partv  = (__half*)(W + 4194304 + 65536);                    // 8192*80*2 = 1.25 MB
    unsigned short* partj = (unsigned short*)(W + 4194304 + 65536 + 1310720);
    unsigned short* nbrB  = (unsigned short*)(W + 4194304 + 65536 + 2 * 1310720);  // 160 KB
    float* blockPart = (float*)(W + 4194304 + 65536 + 2 * 1310720 + 163840);       // 80 KB

    k_extract<<<dim3(N_ROWS), dim3(256), 0, stream>>>(pred, maps, mapsB, sqn, msePart);
    k_knn<<<dim3(N_ROWS / 128, NS), dim3(256), 0, stream>>>(mapsB, sqn, partv, partj);
    k_merge<<<dim3(N_ROWS / 4), dim3(256), 0, stream>>>(partv, partj, nbrB);
    k_pairs<<<dim3(N_ROWS * KNN / 4), dim3(256), 0, stream>>>(pred, maps, nbrB, blockPart);
    k_final<<<dim3(1), dim3(256), 0, stream>>>(msePart, blockPart, lamda, out);
}

// Round 5
// 174.246 us; speedup vs baseline: 5.6566x; 2.3212x over previous
//
#include <hip/hip_runtime.h>
#include <math.h>

#define N_ROWS 8192
#define DIM    256
#define KNN    10
#define FLT_BIG 3.0e38f

typedef __attribute__((ext_vector_type(8))) short bf16x8;
typedef __attribute__((ext_vector_type(4))) float f32x4;

__device__ __forceinline__ unsigned short f2bf(float f) {
    unsigned u = __float_as_uint(f);
    return (unsigned short)((u + 0x7fff + ((u >> 16) & 1)) >> 16);
}
__device__ __forceinline__ float bf2f(unsigned short b) {
    return __uint_as_float(((unsigned)b) << 16);
}

// async global->LDS, 16B per lane; LDS dest = wave-uniform base + lane*16
__device__ __forceinline__ void gl16(const unsigned short* gp, unsigned short* lp) {
    __builtin_amdgcn_global_load_lds(
        (const __attribute__((address_space(1))) unsigned int*)gp,
        (__attribute__((address_space(3))) unsigned int*)lp,
        16, 0, 0);
}

// sorted ascending top-10 insert: 20 branchless u32 ops
__device__ __forceinline__ void ins10(unsigned (&t)[KNN], unsigned v) {
#pragma unroll
    for (int q = 0; q < KNN; ++q) {
        unsigned lo = min(t[q], v);
        v = max(t[q], v);
        t[q] = lo;
    }
}

// merge two sorted-asc 10-lists -> lowest 10 sorted (static-index network)
__device__ __forceinline__ void merge10(unsigned (&a)[KNN], const unsigned (&b)[KNN]) {
    unsigned o[KNN];
#pragma unroll
    for (int i = 0; i < KNN; ++i) {
        unsigned best = min(a[i], b[i]);
#pragma unroll
        for (int j = 0; j < i; ++j)
            best = min(best, max(a[j], b[i - 1 - j]));
        o[i] = best;
    }
#pragma unroll
    for (int i = 0; i < KNN; ++i) a[i] = o[i];
}

// --------------------------- patch extract -> bf16 + sqn + mse part
__global__ __launch_bounds__(256) void k_extract(const float* __restrict__ pred,
                                                 const float* __restrict__ maps,
                                                 unsigned short* __restrict__ mapsB,
                                                 float* __restrict__ sqn,
                                                 float* __restrict__ msePart) {
    int row = blockIdx.x;          // patch index: b*256 + m*16 + n
    int j   = threadIdx.x;         // element within patch: r*16 + c
    int b = row >> 8, m = (row >> 4) & 15, n = row & 15;
    int r = j >> 4, c = j & 15;
    int src = (b << 16) + ((m * 16 + r) << 8) + (n * 16 + c);
    float p = pred[src];
    float q = maps[src];
    unsigned short mb = f2bf(q * 0.01f);
    mapsB[row * DIM + j] = mb;
    float mv = bf2f(mb);
    float sq = mv * mv;
    float d  = q - p;
    float ms = d * d;
    for (int off = 32; off; off >>= 1) {
        sq += __shfl_down(sq, off);
        ms += __shfl_down(ms, off);
    }
    __shared__ float s_sq[4], s_ms[4];
    int wave = threadIdx.x >> 6;
    if ((threadIdx.x & 63) == 0) { s_sq[wave] = sq; s_ms[wave] = ms; }
    __syncthreads();
    if (threadIdx.x == 0) {
        sqn[row] = s_sq[0] + s_sq[1] + s_sq[2] + s_sq[3];
        msePart[row] = s_ms[0] + s_ms[1] + s_ms[2] + s_ms[3];
    }
}

// ------------- MFMA Gram + in-register fold -> per-slice top-10 (packed u32)
// grid (128, 8): 64 i-rows x 1024 j-cols per block; 4 waves, wave = 16-row strip.
__global__ __launch_bounds__(256, 4) void k_knn(const unsigned short* __restrict__ mapsB,
                                                const float* __restrict__ sqn,
                                                unsigned int* __restrict__ part) {
    __shared__ unsigned short As[64 * 64];    //  8 KB
    __shared__ unsigned short Bs[128 * 64];   // 16 KB
    __shared__ float Ssqn[1024];              //  4 KB

    const int tid = threadIdx.x;
    const int l   = tid & 63;
    const int w   = tid >> 6;
    const int i0  = blockIdx.x * 64;
    const int js0 = blockIdx.y * 1024;
    const int l15 = l & 15;
    const int l4  = l >> 4;
    const int rrA = w * 16 + l15;

    for (int e = tid; e < 1024; e += 256) Ssqn[e] = sqn[js0 + e];

    unsigned tops[4][KNN];
#pragma unroll
    for (int q = 0; q < 4; ++q)
#pragma unroll
        for (int s = 0; s < KNN; ++s) tops[q][s] = 0xFFFFFFFFu;

#pragma unroll 1
    for (int tt = 0; tt < 8; ++tt) {
        const int jg0 = js0 + tt * 128;

        f32x4 acc[8];
#pragma unroll
        for (int nn = 0; nn < 8; ++nn)
#pragma unroll
            for (int q = 0; q < 4; ++q) acc[nn][q] = 0.f;

        for (int kt = 0; kt < 4; ++kt) {
            const int k0 = kt * 64;
            __syncthreads();   // prior tile/phase LDS reads done
            {
                int c = w * 128 + l;                 // A chunk, t=0
                int r = c >> 3, c8 = c & 7;
                gl16(&mapsB[(i0 + r) * DIM + k0 + ((c8 ^ (r & 7)) << 3)],
                     &As[(w * 128) * 8]);
                c = w * 128 + 64 + l;                // A chunk, t=1
                r = c >> 3; c8 = c & 7;
                gl16(&mapsB[(i0 + r) * DIM + k0 + ((c8 ^ (r & 7)) << 3)],
                     &As[(w * 128 + 64) * 8]);
            }
#pragma unroll
            for (int t = 0; t < 4; ++t) {            // B chunks
                int c = w * 256 + t * 64 + l;
                int r = c >> 3, c8 = c & 7;
                gl16(&mapsB[(js0 + tt * 128 + r) * DIM + k0 + ((c8 ^ (r & 7)) << 3)],
                     &Bs[(w * 256 + t * 64) * 8]);
            }
            __syncthreads();   // compiler drains vmcnt before barrier (all DMAs landed)

#pragma unroll
            for (int g = 0; g < 2; ++g) {
                const int kb = g * 4 + l4;
                bf16x8 af = *reinterpret_cast<const bf16x8*>(
                    &As[rrA * 64 + ((kb ^ (rrA & 7)) << 3)]);
#pragma unroll
                for (int h = 0; h < 2; ++h) {
                    int cb0 = (h * 4 + 0) * 16 + l15;
                    int cb1 = (h * 4 + 1) * 16 + l15;
                    int cb2 = (h * 4 + 2) * 16 + l15;
                    int cb3 = (h * 4 + 3) * 16 + l15;
                    bf16x8 b0 = *reinterpret_cast<const bf16x8*>(&Bs[cb0 * 64 + ((kb ^ (cb0 & 7)) << 3)]);
                    bf16x8 b1 = *reinterpret_cast<const bf16x8*>(&Bs[cb1 * 64 + ((kb ^ (cb1 & 7)) << 3)]);
                    bf16x8 b2 = *reinterpret_cast<const bf16x8*>(&Bs[cb2 * 64 + ((kb ^ (cb2 & 7)) << 3)]);
                    bf16x8 b3 = *reinterpret_cast<const bf16x8*>(&Bs[cb3 * 64 + ((kb ^ (cb3 & 7)) << 3)]);
                    acc[h * 4 + 0] = __builtin_amdgcn_mfma_f32_16x16x32_bf16(af, b0, acc[h * 4 + 0], 0, 0, 0);
                    acc[h * 4 + 1] = __builtin_amdgcn_mfma_f32_16x16x32_bf16(af, b1, acc[h * 4 + 1], 0, 0, 0);
                    acc[h * 4 + 2] = __builtin_amdgcn_mfma_f32_16x16x32_bf16(af, b2, acc[h * 4 + 2], 0, 0, 0);
                    acc[h * 4 + 3] = __builtin_amdgcn_mfma_f32_16x16x32_bf16(af, b3, acc[h * 4 + 3], 0, 0, 0);
                }
            }
        }

        // fold: quantize to u16 fixed-point, pack with j, branchless sorted insert.
        // v = sqn_j - 2*dot in [-0.074, 0.111] -> u = v*131072 + 32768 well within u16.
#pragma unroll
        for (int nn = 0; nn < 8; ++nn) {
            const int jc = nn * 16 + l15;
            const float sj = Ssqn[tt * 128 + jc];
            const unsigned jj = (unsigned)(jg0 + jc);
#pragma unroll
            for (int q = 0; q < 4; ++q) {
                float v = fmaf(-2.f, acc[nn][q], sj);
                unsigned u = __float2uint_rn(fmaf(v, 131072.f, 32768.f));
                u = min(u, 65535u);
                ins10(tops[q], (u << 16) | jj);
            }
        }
    }

    // merge across the 16 lanes sharing each 4-row group
#pragma unroll
    for (int q = 0; q < 4; ++q) {
#pragma unroll
        for (int off = 1; off <= 8; off <<= 1) {
            unsigned ob[KNN];
#pragma unroll
            for (int s = 0; s < KNN; ++s)
                ob[s] = (unsigned)__shfl_xor((int)tops[q][s], off);
            merge10(tops[q], ob);
        }
    }
    if (l15 == 0) {
        const int rbase = i0 + w * 16 + l4 * 4;
#pragma unroll
        for (int q = 0; q < 4; ++q)
#pragma unroll
            for (int s = 0; s < KNN; ++s)
                part[(rbase + q) * (8 * KNN) + blockIdx.y * KNN + s] = tops[q][s];
    }
}

// -------------------- merge 80 packed partials -> nbr[8192][10]
__global__ __launch_bounds__(256) void k_merge(const unsigned int* __restrict__ part,
                                               unsigned short* __restrict__ nbr) {
    const int row = blockIdx.x * 256 + threadIdx.x;
    unsigned t[KNN];
#pragma unroll
    for (int s = 0; s < KNN; ++s) t[s] = 0xFFFFFFFFu;
    const unsigned int* p = part + row * (8 * KNN);
#pragma unroll 1
    for (int e = 0; e < 8 * KNN; ++e) ins10(t, p[e]);
#pragma unroll
    for (int s = 0; s < KNN; ++s) nbr[row * KNN + s] = (unsigned short)(t[s] & 0xFFFFu);
}

// -------------------- one wave per (row, nbr) pair -> block partial
__global__ __launch_bounds__(256) void k_pairs(const float* __restrict__ pred,
                                               const float* __restrict__ maps,
                                               const unsigned short* __restrict__ nbr,
                                               float* __restrict__ blockPart) {
    const int p = blockIdx.x * 4 + (threadIdx.x >> 6);   // pair 0..81919
    const int l = threadIdx.x & 63;
    const int row = p / KNN;
    const int jj  = (int)nbr[p];

    const int r = l >> 2, cb = (l & 3) * 4;
    const int bi = row >> 8, mi = (row >> 4) & 15, ni = row & 15;
    const int bj = jj  >> 8, mj = (jj  >> 4) & 15, nj = jj  & 15;
    const int ibase = (bi << 16) + ((mi * 16 + r) << 8) + (ni * 16 + cb);
    const int jbase = (bj << 16) + ((mj * 16 + r) << 8) + (nj * 16 + cb);

    const float4 miv = *reinterpret_cast<const float4*>(&maps[ibase]);
    const float4 piv = *reinterpret_cast<const float4*>(&pred[ibase]);
    const float4 mjv = *reinterpret_cast<const float4*>(&maps[jbase]);
    const float4 pjv = *reinterpret_cast<const float4*>(&pred[jbase]);

    float dx = (miv.x - mjv.x) * 0.01f, dy = (miv.y - mjv.y) * 0.01f;
    float dz = (miv.z - mjv.z) * 0.01f, dw = (miv.w - mjv.w) * 0.01f;
    float s2m = dx * dx + dy * dy + dz * dz + dw * dw;
    float s1m = fabsf(dx) + fabsf(dy) + fabsf(dz) + fabsf(dw);
    float ex = (piv.x - pjv.x) * 0.01f, ey = (piv.y - pjv.y) * 0.01f;
    float ez = (piv.z - pjv.z) * 0.01f, ew = (piv.w - pjv.w) * 0.01f;
    float s2p = ex * ex + ey * ey + ez * ez + ew * ew;
    for (int off = 32; off; off >>= 1) {
        s2m += __shfl_down(s2m, off);
        s1m += __shfl_down(s1m, off);
        s2p += __shfl_down(s2p, off);
    }
    __shared__ float wp[4];
    if (l == 0) {
        float d2  = sqrtf(s2m);
        float d1  = s1m + 1e-8f;
        float wgt = expf(-d2 / d1);
        float pd  = sqrtf(fmaxf(s2p, 0.f));
        wp[threadIdx.x >> 6] = pd * wgt;
    }
    __syncthreads();
    if (threadIdx.x == 0)
        blockPart[blockIdx.x] = wp[0] + wp[1] + wp[2] + wp[3];
}

// ---------------------------------------------------------------- final
__global__ __launch_bounds__(256) void k_final(const float* __restrict__ msePart,
                                               const float* __restrict__ blockPart,
                                               const float* __restrict__ lamda,
                                               float* __restrict__ out) {
    const int tid = threadIdx.x;
    float sm = 0.f, sp = 0.f;
    for (int i = tid; i < N_ROWS; i += 256) sm += msePart[i];
    for (int i = tid; i < (N_ROWS * KNN / 4); i += 256) sp += blockPart[i];
    for (int off = 32; off; off >>= 1) {
        sm += __shfl_down(sm, off);
        sp += __shfl_down(sp, off);
    }
    __shared__ float s_m[4], s_p[4];
    int wave = tid >> 6;
    if ((tid & 63) == 0) { s_m[wave] = sm; s_p[wave] = sp; }
    __syncthreads();
    if (tid == 0) {
        float mse   = (s_m[0] + s_m[1] + s_m[2] + s_m[3]) / 2097152.0f;
        float loss2 = (s_p[0] + s_p[1] + s_p[2] + s_p[3]) / (8192.0f * 8192.0f);
        out[0] = mse + loss2 * lamda[0];
    }
}

extern "C" void kernel_launch(void* const* d_in, const int* in_sizes, int n_in,
                              void* d_out, int out_size, void* d_ws, size_t ws_size,
                              hipStream_t stream) {
    const float* pred  = (const float*)d_in[0];
    const float* maps  = (const float*)d_in[1];
    const float* lamda = (const float*)d_in[3];
    float* out = (float*)d_out;

    char* W = (char*)d_ws;
    unsigned short* mapsB = (unsigned short*)W;                    // 4 MB
    float* sqn       = (float*)(W + 4194304);                      // 32 KB
    float* msePart   = (float*)(W + 4194304 + 32768);              // 32 KB
    unsigned int* part = (unsigned int*)(W + 4259840);             // 8192*80*4 = 2.5 MB
    unsigned short* nbrB = (unsigned short*)(W + 4259840 + 2621440);       // 160 KB
    float* blockPart = (float*)(W + 4259840 + 2621440 + 163840);           // 80 KB

    k_extract<<<dim3(N_ROWS), dim3(256), 0, stream>>>(pred, maps, mapsB, sqn, msePart);
    k_knn<<<dim3(N_ROWS / 64, 8), dim3(256), 0, stream>>>(mapsB, sqn, part);
    k_merge<<<dim3(N_ROWS / 256), dim3(256), 0, stream>>>(part, nbrB);
    k_pairs<<<dim3(N_ROWS * KNN / 4), dim3(256), 0, stream>>>(pred, maps, nbrB, blockPart);
    k_final<<<dim3(1), dim3(256), 0, stream>>>(msePart, blockPart, lamda, out);
}

// Round 6
// 140.628 us; speedup vs baseline: 7.0089x; 1.2391x over previous
//
#include <hip/hip_runtime.h>
#include <math.h>

#define N_ROWS 8192
#define DIM    256
#define KNN    10

typedef __attribute__((ext_vector_type(8))) short bf16x8;
typedef __attribute__((ext_vector_type(4))) float f32x4;

__device__ __forceinline__ unsigned short f2bf(float f) {
    unsigned u = __float_as_uint(f);
    return (unsigned short)((u + 0x7fff + ((u >> 16) & 1)) >> 16);
}
__device__ __forceinline__ float bf2f(unsigned short b) {
    return __uint_as_float(((unsigned)b) << 16);
}

// async global->LDS, 16B per lane; LDS dest = wave-uniform base + lane*16
__device__ __forceinline__ void gl16(const unsigned short* gp, unsigned short* lp) {
    __builtin_amdgcn_global_load_lds(
        (const __attribute__((address_space(1))) unsigned int*)gp,
        (__attribute__((address_space(3))) unsigned int*)lp,
        16, 0, 0);
}

// sorted ascending top-10 insert: 20 branchless u32 ops
__device__ __forceinline__ void ins10(unsigned (&t)[KNN], unsigned v) {
#pragma unroll
    for (int q = 0; q < KNN; ++q) {
        unsigned lo = min(t[q], v);
        v = max(t[q], v);
        t[q] = lo;
    }
}

// merge sorted-10 list with sorted pair (m <= M): keep lowest 10 (29 ops)
__device__ __forceinline__ void merge10_2(unsigned (&a)[KNN], unsigned m, unsigned M) {
    unsigned r[KNN];
    r[0] = min(a[0], m);
    r[1] = min(min(a[1], max(a[0], m)), M);
#pragma unroll
    for (int i = 2; i < KNN; ++i)
        r[i] = min(min(a[i], max(a[i - 1], m)), max(a[i - 2], M));
#pragma unroll
    for (int i = 0; i < KNN; ++i) a[i] = r[i];
}

// merge two sorted-asc 10-lists -> lowest 10 sorted (static-index network)
__device__ __forceinline__ void merge10(unsigned (&a)[KNN], const unsigned (&b)[KNN]) {
    unsigned o[KNN];
#pragma unroll
    for (int i = 0; i < KNN; ++i) {
        unsigned best = min(a[i], b[i]);
#pragma unroll
        for (int j = 0; j < i; ++j)
            best = min(best, max(a[j], b[i - 1 - j]));
        o[i] = best;
    }
#pragma unroll
    for (int i = 0; i < KNN; ++i) a[i] = o[i];
}

// --------------------------- patch extract -> bf16 (maps+pred) + sqn + mse part
__global__ __launch_bounds__(256) void k_extract(const float* __restrict__ pred,
                                                 const float* __restrict__ maps,
                                                 unsigned short* __restrict__ mapsB,
                                                 unsigned short* __restrict__ predB,
                                                 float* __restrict__ sqn,
                                                 float* __restrict__ msePart) {
    int row = blockIdx.x;          // patch index: b*256 + m*16 + n
    int j   = threadIdx.x;         // element within patch: r*16 + c
    int b = row >> 8, m = (row >> 4) & 15, n = row & 15;
    int r = j >> 4, c = j & 15;
    int src = (b << 16) + ((m * 16 + r) << 8) + (n * 16 + c);
    float p = pred[src];
    float q = maps[src];
    unsigned short mb = f2bf(q * 0.01f);
    mapsB[row * DIM + j] = mb;
    predB[row * DIM + j] = f2bf(p * 0.01f);
    float mv = bf2f(mb);
    float sq = mv * mv;
    float d  = q - p;
    float ms = d * d;
    for (int off = 32; off; off >>= 1) {
        sq += __shfl_down(sq, off);
        ms += __shfl_down(ms, off);
    }
    __shared__ float s_sq[4], s_ms[4];
    int wave = threadIdx.x >> 6;
    if ((threadIdx.x & 63) == 0) { s_sq[wave] = sq; s_ms[wave] = ms; }
    __syncthreads();
    if (threadIdx.x == 0) {
        sqn[row] = s_sq[0] + s_sq[1] + s_sq[2] + s_sq[3];
        msePart[row] = s_ms[0] + s_ms[1] + s_ms[2] + s_ms[3];
    }
}

// ------------- MFMA Gram + in-register fold -> per-slice top-10 (packed u32)
// grid (128, 8): 64 i-rows x 1024 j-cols per block; 4 waves, wave = 16-row strip.
__global__ __launch_bounds__(256, 4) void k_knn(const unsigned short* __restrict__ mapsB,
                                                const float* __restrict__ sqn,
                                                unsigned int* __restrict__ part) {
    __shared__ unsigned short As[64 * 64];    //  8 KB
    __shared__ unsigned short Bs[128 * 64];   // 16 KB
    __shared__ float SJQ[1024];               //  4 KB (pre-scaled sqn)

    const int tid = threadIdx.x;
    const int l   = tid & 63;
    const int w   = tid >> 6;
    const int i0  = blockIdx.x * 64;
    const int js0 = blockIdx.y * 1024;
    const int l15 = l & 15;
    const int l4  = l >> 4;
    const int c7  = l15 & 7;                 // == (row&7) for ALL fragment rows
    const int aBase = (w * 16 + l15) * 64;   // A-fragment row base (shorts)
    int bBase[8];
#pragma unroll
    for (int nn = 0; nn < 8; ++nn) bBase[nn] = (nn * 16 + l15) * 64;

    for (int e = tid; e < 1024; e += 256)
        SJQ[e] = fmaf(sqn[js0 + e], 131072.f, 32768.f);

    unsigned tops[4][KNN];
#pragma unroll
    for (int q = 0; q < 4; ++q)
#pragma unroll
        for (int s = 0; s < KNN; ++s) tops[q][s] = 0xFFFFFFFFu;

#pragma unroll 1
    for (int tt = 0; tt < 8; ++tt) {
        const int jg0 = js0 + tt * 128;

        f32x4 acc[8];
#pragma unroll
        for (int nn = 0; nn < 8; ++nn)
#pragma unroll
            for (int q = 0; q < 4; ++q) acc[nn][q] = 0.f;

        for (int kt = 0; kt < 4; ++kt) {
            const int k0 = kt * 64;
            __syncthreads();   // prior tile/phase LDS reads done
            {
                int c = w * 128 + l;                 // A chunk, t=0
                int r = c >> 3, c8 = c & 7;
                gl16(&mapsB[(i0 + r) * DIM + k0 + ((c8 ^ (r & 7)) << 3)],
                     &As[(w * 128) * 8]);
                c = w * 128 + 64 + l;                // A chunk, t=1
                r = c >> 3; c8 = c & 7;
                gl16(&mapsB[(i0 + r) * DIM + k0 + ((c8 ^ (r & 7)) << 3)],
                     &As[(w * 128 + 64) * 8]);
            }
#pragma unroll
            for (int t = 0; t < 4; ++t) {            // B chunks
                int c = w * 256 + t * 64 + l;
                int r = c >> 3, c8 = c & 7;
                gl16(&mapsB[(jg0 + r) * DIM + k0 + ((c8 ^ (r & 7)) << 3)],
                     &Bs[(w * 256 + t * 64) * 8]);
            }
            __syncthreads();   // vmcnt drained before barrier (all DMAs landed)

#pragma unroll
            for (int g = 0; g < 2; ++g) {
                const int kb = g * 4 + l4;
                const int swz = (kb ^ c7) << 3;
                bf16x8 af = *reinterpret_cast<const bf16x8*>(&As[aBase + swz]);
#pragma unroll
                for (int h = 0; h < 2; ++h) {
                    bf16x8 b0 = *reinterpret_cast<const bf16x8*>(&Bs[bBase[h * 4 + 0] + swz]);
                    bf16x8 b1 = *reinterpret_cast<const bf16x8*>(&Bs[bBase[h * 4 + 1] + swz]);
                    bf16x8 b2 = *reinterpret_cast<const bf16x8*>(&Bs[bBase[h * 4 + 2] + swz]);
                    bf16x8 b3 = *reinterpret_cast<const bf16x8*>(&Bs[bBase[h * 4 + 3] + swz]);
                    acc[h * 4 + 0] = __builtin_amdgcn_mfma_f32_16x16x32_bf16(af, b0, acc[h * 4 + 0], 0, 0, 0);
                    acc[h * 4 + 1] = __builtin_amdgcn_mfma_f32_16x16x32_bf16(af, b1, acc[h * 4 + 1], 0, 0, 0);
                    acc[h * 4 + 2] = __builtin_amdgcn_mfma_f32_16x16x32_bf16(af, b2, acc[h * 4 + 2], 0, 0, 0);
                    acc[h * 4 + 3] = __builtin_amdgcn_mfma_f32_16x16x32_bf16(af, b3, acc[h * 4 + 3], 0, 0, 0);
                }
            }
        }

        // fold: u = cvt(SJQ_j - 262144*dot) packs to (u16<<16)|j; pairwise (10,2) merge.
#pragma unroll
        for (int np = 0; np < 4; ++np) {
            const int n0 = 2 * np, n1 = 2 * np + 1;
            const float sj0 = SJQ[tt * 128 + n0 * 16 + l15];
            const float sj1 = SJQ[tt * 128 + n1 * 16 + l15];
            const unsigned j0 = (unsigned)(jg0 + n0 * 16 + l15);
            const unsigned j1 = (unsigned)(jg0 + n1 * 16 + l15);
#pragma unroll
            for (int q = 0; q < 4; ++q) {
                unsigned u0 = min(__float2uint_rn(fmaf(acc[n0][q], -262144.f, sj0)), 65535u);
                unsigned u1 = min(__float2uint_rn(fmaf(acc[n1][q], -262144.f, sj1)), 65535u);
                unsigned p0 = (u0 << 16) | j0;
                unsigned p1 = (u1 << 16) | j1;
                merge10_2(tops[q], min(p0, p1), max(p0, p1));
            }
        }
    }

    // merge across the 16 lanes sharing each 4-row group
#pragma unroll
    for (int q = 0; q < 4; ++q) {
#pragma unroll
        for (int off = 1; off <= 8; off <<= 1) {
            unsigned ob[KNN];
#pragma unroll
            for (int s = 0; s < KNN; ++s)
                ob[s] = (unsigned)__shfl_xor((int)tops[q][s], off);
            merge10(tops[q], ob);
        }
    }
    if (l15 == 0) {
        const int rbase = i0 + w * 16 + l4 * 4;
#pragma unroll
        for (int q = 0; q < 4; ++q)
#pragma unroll
            for (int s = 0; s < KNN; ++s)
                part[(rbase + q) * (8 * KNN) + blockIdx.y * KNN + s] = tops[q][s];
    }
}

// -------------------- merge 80 packed partials -> nbr[8192][10]
__global__ __launch_bounds__(256) void k_merge(const unsigned int* __restrict__ part,
                                               unsigned short* __restrict__ nbr) {
    const int row = blockIdx.x * 256 + threadIdx.x;
    unsigned t[KNN];
#pragma unroll
    for (int s = 0; s < KNN; ++s) t[s] = 0xFFFFFFFFu;
    const unsigned int* p = part + row * (8 * KNN);
#pragma unroll 1
    for (int e = 0; e < 8 * KNN; ++e) ins10(t, p[e]);
#pragma unroll
    for (int s = 0; s < KNN; ++s) nbr[row * KNN + s] = (unsigned short)(t[s] & 0xFFFFu);
}

// -------------------- one wave per row: 10 neighbor terms from bf16 vectors
__global__ __launch_bounds__(256) void k_pairs(const unsigned short* __restrict__ mapsB,
                                               const unsigned short* __restrict__ predB,
                                               const unsigned short* __restrict__ nbr,
                                               float* __restrict__ pairPart) {
    const int row = blockIdx.x * 4 + (threadIdx.x >> 6);
    const int l = threadIdx.x & 63;

    const ushort4 m4 = *reinterpret_cast<const ushort4*>(&mapsB[row * DIM + l * 4]);
    const ushort4 p4 = *reinterpret_cast<const ushort4*>(&predB[row * DIM + l * 4]);
    float mi[4] = { bf2f(m4.x), bf2f(m4.y), bf2f(m4.z), bf2f(m4.w) };
    float pi[4] = { bf2f(p4.x), bf2f(p4.y), bf2f(p4.z), bf2f(p4.w) };

    float wsum = 0.f;
#pragma unroll 1
    for (int nb = 0; nb < KNN; ++nb) {
        const int jj = (int)nbr[row * KNN + nb];
        const ushort4 mj4 = *reinterpret_cast<const ushort4*>(&mapsB[jj * DIM + l * 4]);
        const ushort4 pj4 = *reinterpret_cast<const ushort4*>(&predB[jj * DIM + l * 4]);
        float s2m = 0.f, s1m = 0.f, s2p = 0.f;
        float mj[4] = { bf2f(mj4.x), bf2f(mj4.y), bf2f(mj4.z), bf2f(mj4.w) };
        float pj[4] = { bf2f(pj4.x), bf2f(pj4.y), bf2f(pj4.z), bf2f(pj4.w) };
#pragma unroll
        for (int e = 0; e < 4; ++e) {
            float dm = mi[e] - mj[e];
            float dp = pi[e] - pj[e];
            s2m = fmaf(dm, dm, s2m);
            s1m += fabsf(dm);
            s2p = fmaf(dp, dp, s2p);
        }
        for (int off = 32; off; off >>= 1) {
            s2m += __shfl_down(s2m, off);
            s1m += __shfl_down(s1m, off);
            s2p += __shfl_down(s2p, off);
        }
        if (l == 0) {
            float d2  = sqrtf(s2m);
            float d1  = s1m + 1e-8f;
            float wgt = expf(-d2 / d1);
            float pd  = sqrtf(fmaxf(s2p, 0.f));
            wsum += pd * wgt;
        }
    }
    if (l == 0) pairPart[row] = wsum;
}

// ---------------------------------------------------------------- final
__global__ __launch_bounds__(256) void k_final(const float* __restrict__ msePart,
                                               const float* __restrict__ pairPart,
                                               const float* __restrict__ lamda,
                                               float* __restrict__ out) {
    const int tid = threadIdx.x;
    float sm = 0.f, sp = 0.f;
    for (int i = tid; i < N_ROWS; i += 256) { sm += msePart[i]; sp += pairPart[i]; }
    for (int off = 32; off; off >>= 1) {
        sm += __shfl_down(sm, off);
        sp += __shfl_down(sp, off);
    }
    __shared__ float s_m[4], s_p[4];
    int wave = tid >> 6;
    if ((tid & 63) == 0) { s_m[wave] = sm; s_p[wave] = sp; }
    __syncthreads();
    if (tid == 0) {
        float mse   = (s_m[0] + s_m[1] + s_m[2] + s_m[3]) / 2097152.0f;
        float loss2 = (s_p[0] + s_p[1] + s_p[2] + s_p[3]) / (8192.0f * 8192.0f);
        out[0] = mse + loss2 * lamda[0];
    }
}

extern "C" void kernel_launch(void* const* d_in, const int* in_sizes, int n_in,
                              void* d_out, int out_size, void* d_ws, size_t ws_size,
                              hipStream_t stream) {
    const float* pred  = (const float*)d_in[0];
    const float* maps  = (const float*)d_in[1];
    const float* lamda = (const float*)d_in[3];
    float* out = (float*)d_out;

    char* W = (char*)d_ws;
    unsigned short* mapsB = (unsigned short*)W;                    // 4 MB
    unsigned short* predB = (unsigned short*)(W + 4194304);        // 4 MB
    float* sqn       = (float*)(W + 8388608);                      // 32 KB
    float* msePart   = (float*)(W + 8388608 + 32768);              // 32 KB
    float* pairPart  = (float*)(W + 8388608 + 65536);              // 32 KB
    unsigned int* part = (unsigned int*)(W + 8388608 + 98304);     // 2.5 MB
    unsigned short* nbrB = (unsigned short*)(W + 8388608 + 98304 + 2621440); // 160 KB

    k_extract<<<dim3(N_ROWS), dim3(256), 0, stream>>>(pred, maps, mapsB, predB, sqn, msePart);
    k_knn<<<dim3(N_ROWS / 64, 8), dim3(256), 0, stream>>>(mapsB, sqn, part);
    k_merge<<<dim3(N_ROWS / 256), dim3(256), 0, stream>>>(part, nbrB);
    k_pairs<<<dim3(N_ROWS / 4), dim3(256), 0, stream>>>(mapsB, predB, nbrB, pairPart);
    k_final<<<dim3(1), dim3(256), 0, stream>>>(msePart, pairPart, lamda, out);
}